// Round 3
// baseline (213.028 us; speedup 1.0000x reference)
//
#include <hip/hip_runtime.h>
#include <hip/hip_bf16.h>

#define LSP 4096   // L = H*W
#define NC  256    // C
#define NH  128    // C/2
#define KB  64     // kv tile
#define QW  64     // q rows per wave
#define SPLIT 4    // kv split factor
#define NTILE ((LSP / SPLIT) / KB)   // 16

typedef __attribute__((ext_vector_type(8))) short short8;
typedef __attribute__((ext_vector_type(4))) float f32x4;
typedef __attribute__((ext_vector_type(4))) unsigned int u32x4;
typedef __attribute__((ext_vector_type(2))) unsigned int u32x2;
typedef __hip_bfloat16 bf16;

#define MFMA16(a,b,c) __builtin_amdgcn_mfma_f32_16x16x32_bf16((a),(b),(c),0,0,0)

typedef __attribute__((address_space(1))) const void gas_t;
typedef __attribute__((address_space(3))) void las_t;
#define GLDS16(g, l) __builtin_amdgcn_global_load_lds((gas_t*)(g), (las_t*)(l), 16, 0, 0)

static __device__ __forceinline__ unsigned short f2bf(float f) {
  bf16 h = __float2bfloat16(f);
  return __builtin_bit_cast(unsigned short, h);
}
static __device__ __forceinline__ unsigned int packbf2(float a, float b) {
  return (unsigned int)f2bf(a) | ((unsigned int)f2bf(b) << 16);
}
static __device__ __forceinline__ float bf2f(unsigned short u) {
  return __builtin_bit_cast(float, (unsigned int)u << 16);
}

// ---------- merged: weights->bf16 + bias concat (blocks 0..511) | SRM stats (512..1535)
__global__ __launch_bounds__(256) void k_pre(const float* __restrict__ a0,
    const float* __restrict__ a1, const float* __restrict__ a2,
    const float* __restrict__ a3, const float* __restrict__ tb,
    const float* __restrict__ pb, bf16* __restrict__ dst, float* __restrict__ bcat,
    const float* __restrict__ x, const float* __restrict__ cfc,
    float* __restrict__ gate) {
  int b = blockIdx.x;
  if (b < 512) {
    int i = b * 256 + threadIdx.x;
    int seg = i >> 15, off = i & 32767;
    const float* s = (seg == 0) ? a0 : (seg == 1) ? a1 : (seg == 2) ? a2 : a3;
    dst[i] = __float2bfloat16(s[off]);
    if (b == 0)
      bcat[threadIdx.x] = threadIdx.x < 128 ? tb[threadIdx.x] : pb[threadIdx.x - 128];
    return;
  }
  int nc = b - 512;   // n*C + c
  const float4* x4 = (const float4*)(x + (size_t)nc * LSP);
  float s = 0.f, q = 0.f;
  for (int i = threadIdx.x; i < LSP / 4; i += 256) {
    float4 v = x4[i];
    s += v.x + v.y + v.z + v.w;
    q += v.x * v.x + v.y * v.y + v.z * v.z + v.w * v.w;
  }
#pragma unroll
  for (int o = 32; o > 0; o >>= 1) { s += __shfl_xor(s, o); q += __shfl_xor(q, o); }
  __shared__ float rs[4], rq[4];
  int w = threadIdx.x >> 6;
  if ((threadIdx.x & 63) == 0) { rs[w] = s; rq[w] = q; }
  __syncthreads();
  if (threadIdx.x == 0) {
    float S = rs[0] + rs[1] + rs[2] + rs[3];
    float Q = rq[0] + rq[1] + rq[2] + rq[3];
    float mean = S / (float)LSP;
    float var = (Q - S * S / (float)LSP) / (float)(LSP - 1) + 1e-5f;
    float sd = sqrtf(var);
    int c = nc & (NC - 1);
    float z = mean * cfc[2 * c] + sd * cfc[2 * c + 1];
    gate[nc] = 1.f / (1.f + __expf(-z));
  }
}

// ---------- s_t[n][l][c] = bf16(x[n][c][l] * gate[n][c]) ----------
__global__ __launch_bounds__(256) void k_scale_t(const float* __restrict__ x,
    const float* __restrict__ gate, bf16* __restrict__ s_t) {
  int n = blockIdx.z;
  int c0 = blockIdx.y * 32;
  int l = blockIdx.x * 256 + threadIdx.x;
  unsigned int pk[16];
#pragma unroll
  for (int i = 0; i < 32; i += 2) {
    int c = c0 + i;
    float g0 = gate[n * NC + c];
    float g1 = gate[n * NC + c + 1];
    float v0 = x[((size_t)(n * NC + c)) * LSP + l] * g0;
    float v1 = x[((size_t)(n * NC + c + 1)) * LSP + l] * g1;
    pk[i >> 1] = packbf2(v0, v1);
  }
  u32x4* dst = (u32x4*)(s_t + ((size_t)n * LSP + l) * NC + c0);
#pragma unroll
  for (int k = 0; k < 4; ++k) dst[k] = ((const u32x4*)pk)[k];
}

// ---------- generic NT GEMM body: D[M,N] = A[M,K] * B[N,K]^T + bias ----------
static __device__ __forceinline__ void gemm_nt_body(const bf16* __restrict__ A,
    const bf16* __restrict__ B, const float* __restrict__ bias, int bias_row,
    bf16* __restrict__ D, int Nd, int Kd, int bx) {
  int tn = Nd >> 6;
  int m0 = (bx / tn) * 64, n0 = (bx % tn) * 64;
  int tid = threadIdx.x, w = tid >> 6, lane = tid & 63;
  int lo = lane & 15, g = lane >> 4;
  f32x4 zero = {0.f, 0.f, 0.f, 0.f};
  f32x4 acc[4];
#pragma unroll
  for (int i = 0; i < 4; ++i) acc[i] = zero;
  for (int kc = 0; kc < Kd; kc += 32) {
    short8 bfr = *(const short8*)(B + (size_t)(n0 + w * 16 + lo) * Kd + kc + g * 8);
#pragma unroll
    for (int i = 0; i < 4; ++i) {
      short8 afr = *(const short8*)(A + (size_t)(m0 + 16 * i + lo) * Kd + kc + g * 8);
      acc[i] = MFMA16(afr, bfr, acc[i]);
    }
  }
  int col = n0 + w * 16 + lo;
#pragma unroll
  for (int i = 0; i < 4; ++i)
#pragma unroll
    for (int r = 0; r < 4; ++r) {
      int row = m0 + 16 * i + g * 4 + r;
      float bv = bias_row ? bias[row] : bias[col];
      D[(size_t)row * Nd + col] = __float2bfloat16(acc[i][r] + bv);
    }
}

// ---------- merged projection GEMMs: thph (bx<256) | gT (bx>=256) ----------
__global__ __launch_bounds__(256) void k_gemms(const bf16* __restrict__ s_t,
    const bf16* __restrict__ wbf, const float* __restrict__ bcat,
    const float* __restrict__ g_b, bf16* __restrict__ thph, bf16* __restrict__ gTb) {
  int z = blockIdx.z, bx = blockIdx.x;
  if (bx < 256) {
    gemm_nt_body(s_t + (size_t)z * LSP * NC, wbf, bcat, 0,
                 thph + (size_t)z * LSP * 256, 256, NC, bx);
  } else {
    gemm_nt_body(wbf + 65536, s_t + (size_t)z * LSP * NC, g_b, 1,
                 gTb + (size_t)z * NH * LSP, LSP, NC, bx - 256);
  }
}

// ---------- flash attention, kv-split, 64 q/wave, 3-deep counted-vmcnt pipe --
__global__ __launch_bounds__(256, 1) void k_attn(const bf16* __restrict__ thph,
    const bf16* __restrict__ gT, bf16* __restrict__ Opart, float* __restrict__ ml) {
  __shared__ bf16 Kl[3][KB * NH];    // [j][k] 256B rows, chunk ^= (j&7)   48 KB
  __shared__ bf16 Vl[3][NH * KB];    // [d][j] 128B rows, chunk ^= (d&7)   48 KB
  __shared__ bf16 Pl[4][QW * KB];    // per-wave [q][j] 128B rows, ^(q&7)  32 KB

  const int n = blockIdx.z, sp = blockIdx.y;
  const int tid = threadIdx.x, w = tid >> 6, lane = tid & 63;
  const int lo = lane & 15, g = lane >> 4;
  const int swz = (lo & 7) << 4;

  const bf16* thn = thph + (size_t)n * LSP * 256;
  const bf16* gv  = gT + (size_t)n * NH * LSP;
  const int q0 = blockIdx.x * 256 + w * QW;
  const int j0base = sp * (LSP / SPLIT);

  // Q B-frags for 4 q-subtiles (64 VGPR, loop-invariant)
  short8 qf[4][4];
#pragma unroll
  for (int qs = 0; qs < 4; ++qs)
#pragma unroll
    for (int kc = 0; kc < 4; ++kc)
      qf[qs][kc] = *(const short8*)(thn + (size_t)(q0 + qs * 16 + lo) * 256 + kc * 32 + g * 8);

  // staging offsets: source pre-swizzled, LDS dest linear (rule 21)
  size_t koff[4], voff[4];
  int ldso[4];
#pragma unroll
  for (int i = 0; i < 4; ++i) {
    int ci = i * 256 + tid;
    int kj = ci >> 4, kcc = ci & 15;
    koff[i] = (size_t)kj * 256 + 128 + ((kcc ^ (kj & 7)) * 8);
    int vd = ci >> 3, vc2 = ci & 7;
    voff[i] = (size_t)vd * LSP + ((vc2 ^ (vd & 7)) * 8);
    ldso[i] = ci * 16;
  }

#define STAGE(JT, BUF) do { \
    const bf16* ksrc = thn + (size_t)(j0base + (JT) * KB) * 256; \
    const bf16* vsrc = gv + (j0base + (JT) * KB); \
    char* kdst = (char*)&Kl[BUF][0]; \
    char* vdst = (char*)&Vl[BUF][0]; \
    _Pragma("unroll") \
    for (int i = 0; i < 4; ++i) { \
      GLDS16(ksrc + koff[i], kdst + ldso[i]); \
      GLDS16(vsrc + voff[i], vdst + ldso[i]); \
    } } while (0)

  f32x4 zero = {0.f, 0.f, 0.f, 0.f};
  f32x4 acc[4][8];
#pragma unroll
  for (int qs = 0; qs < 4; ++qs)
#pragma unroll
    for (int dc = 0; dc < 8; ++dc) acc[qs][dc] = zero;
  float mv[4] = {-1e30f, -1e30f, -1e30f, -1e30f};
  float ls[4] = {0.f, 0.f, 0.f, 0.f};

  STAGE(0, 0);
  STAGE(1, 1);

  char* pwb = (char*)&Pl[w][0];

  for (int t = 0; t < NTILE; ++t) {
    int cur = t % 3;
    // wait own tile-t loads (leave t+1's 8 in flight); then sync all waves
    if (t < NTILE - 1) asm volatile("s_waitcnt vmcnt(8)" ::: "memory");
    else               asm volatile("s_waitcnt vmcnt(0)" ::: "memory");
    __builtin_amdgcn_sched_barrier(0);
    __builtin_amdgcn_s_barrier();
    if (t + 2 < NTILE) STAGE(t + 2, (t + 2) % 3);   // into buffer freed by t-1

    const char* Kb = (const char*)&Kl[cur][0];
    const char* Vb = (const char*)&Vl[cur][0];

    // K-frag register cache: read K tile once, reuse across 4 q-subtiles
    short8 kfr[4][4];   // [jt][kc]
#pragma unroll
    for (int jt = 0; jt < 4; ++jt)
#pragma unroll
      for (int kc = 0; kc < 4; ++kc)
        kfr[jt][kc] = *(const short8*)(Kb + (jt * 16 + lo) * 256 + ((kc * 64 + g * 16) ^ swz));

#pragma unroll
    for (int qs = 0; qs < 4; ++qs) {
      f32x4 st[4];
#pragma unroll
      for (int jt = 0; jt < 4; ++jt) st[jt] = zero;
#pragma unroll
      for (int kc = 0; kc < 4; ++kc)
#pragma unroll
        for (int jt = 0; jt < 4; ++jt)
          st[jt] = MFMA16(kfr[jt][kc], qf[qs][kc], st[jt]);

      // tile max for q = lo (replicated over lane-groups)
      float t0 = fmaxf(fmaxf(st[0][0], st[0][1]), fmaxf(st[0][2], st[0][3]));
      float t1 = fmaxf(fmaxf(st[1][0], st[1][1]), fmaxf(st[1][2], st[1][3]));
      float t2 = fmaxf(fmaxf(st[2][0], st[2][1]), fmaxf(st[2][2], st[2][3]));
      float t3 = fmaxf(fmaxf(st[3][0], st[3][1]), fmaxf(st[3][2], st[3][3]));
      float tq = fmaxf(fmaxf(t0, t1), fmaxf(t2, t3));
      tq = fmaxf(tq, __shfl_xor(tq, 16));
      tq = fmaxf(tq, __shfl_xor(tq, 32));

      // defer-max (T13, THR=8)
      if (__any(tq > mv[qs] + 8.f)) {
        float nm = fmaxf(mv[qs], tq);
        float a = __expf(mv[qs] - nm);
        mv[qs] = nm; ls[qs] *= a;
#pragma unroll
        for (int r = 0; r < 4; ++r) {
          float b = __shfl(a, g * 4 + r);
#pragma unroll
          for (int dc = 0; dc < 8; ++dc) acc[qs][dc][r] *= b;
        }
      }

      // P = exp(S - m) -> swizzled per-wave LDS
      float mm = mv[qs], psum = 0.f;
      int rowb = (qs * 16 + lo) * 128;
#pragma unroll
      for (int jt = 0; jt < 4; ++jt) {
        float e0 = __expf(st[jt][0] - mm);
        float e1 = __expf(st[jt][1] - mm);
        float e2 = __expf(st[jt][2] - mm);
        float e3 = __expf(st[jt][3] - mm);
        psum += (e0 + e1) + (e2 + e3);
        u32x2 pk;
        pk.x = packbf2(e0, e1);
        pk.y = packbf2(e2, e3);
        *(u32x2*)(pwb + rowb + ((jt * 32 + g * 8) ^ swz)) = pk;
      }
      psum += __shfl_xor(psum, 16);
      psum += __shfl_xor(psum, 32);
      ls[qs] += psum;
    }

    asm volatile("" ::: "memory");  // order P ds_writes before ds_reads
    // PV: V-frag shared across 4 q-subtiles
#pragma unroll
    for (int kc2 = 0; kc2 < 2; ++kc2) {
      int kbb = kc2 * 64 + g * 16;
      short8 pa[4];
#pragma unroll
      for (int qs = 0; qs < 4; ++qs)
        pa[qs] = *(const short8*)(pwb + (qs * 16 + lo) * 128 + (kbb ^ swz));
#pragma unroll
      for (int dc = 0; dc < 8; ++dc) {
        int d = dc * 16 + lo;
        short8 vb = *(const short8*)(Vb + d * 128 + (kbb ^ ((d & 7) << 4)));
#pragma unroll
        for (int qs = 0; qs < 4; ++qs)
          acc[qs][dc] = MFMA16(pa[qs], vb, acc[qs][dc]);
      }
    }
  }

  // epilogue: unnormalized partial O (bf16) + (m, lsum)
  bf16* opb = Opart + ((size_t)(sp * 4 + n) * LSP + q0) * NH;
#pragma unroll
  for (int qs = 0; qs < 4; ++qs)
#pragma unroll
    for (int dc = 0; dc < 8; ++dc)
#pragma unroll
      for (int r = 0; r < 4; ++r)
        opb[(size_t)(qs * 16 + g * 4 + r) * NH + dc * 16 + lo] =
            __float2bfloat16(acc[qs][dc][r]);
  if (g == 0) {
    float2* mlp = (float2*)ml + (size_t)(sp * 4 + n) * LSP + q0;
#pragma unroll
    for (int qs = 0; qs < 4; ++qs)
      mlp[qs * 16 + lo] = make_float2(mv[qs], ls[qs]);
  }
#undef STAGE
}

// ---------- fused combine + out-proj + residual ----------
// out[c][l] = x*gate + out_b[c] + sum_ch out_w[c][ch] * (sum_s sc_s[l]*Opart[s][l][ch])
__global__ __launch_bounds__(256) void k_final(const bf16* __restrict__ Wo,
    const bf16* __restrict__ Opart, const float* __restrict__ ml,
    const float* __restrict__ x, const float* __restrict__ gate,
    const float* __restrict__ ob, float* __restrict__ out) {
  int n = blockIdx.z;
  int m0 = (blockIdx.x >> 6) * 64, n0 = (blockIdx.x & 63) * 64;
  int tid = threadIdx.x, w = tid >> 6, lane = tid & 63;
  int lo = lane & 15, g = lane >> 4;
  int col = n0 + w * 16 + lo;

  // split-combine scales for this lane's l = col
  float sc[SPLIT];
  {
    float2 m4[SPLIT];
    float mx = -1e30f;
#pragma unroll
    for (int s = 0; s < SPLIT; ++s) {
      m4[s] = ((const float2*)ml)[(size_t)(s * 4 + n) * LSP + col];
      mx = fmaxf(mx, m4[s].x);
    }
    float den = 0.f;
#pragma unroll
    for (int s = 0; s < SPLIT; ++s) { sc[s] = __expf(m4[s].x - mx); den += m4[s].y * sc[s]; }
    float inv = 1.f / den;
#pragma unroll
    for (int s = 0; s < SPLIT; ++s) sc[s] *= inv;
  }

  f32x4 zero = {0.f, 0.f, 0.f, 0.f};
  f32x4 acc[4];
#pragma unroll
  for (int i = 0; i < 4; ++i) acc[i] = zero;
#pragma unroll
  for (int kc = 0; kc < 4; ++kc) {
    float bv[8] = {0.f, 0.f, 0.f, 0.f, 0.f, 0.f, 0.f, 0.f};
#pragma unroll
    for (int s = 0; s < SPLIT; ++s) {
      short8 v = *(const short8*)(Opart + ((size_t)(s * 4 + n) * LSP + col) * NH + kc * 32 + g * 8);
#pragma unroll
      for (int e = 0; e < 8; ++e)
        bv[e] += sc[s] * bf2f((unsigned short)v[e]);
    }
    u32x4 pk4;
    pk4.x = packbf2(bv[0], bv[1]); pk4.y = packbf2(bv[2], bv[3]);
    pk4.z = packbf2(bv[4], bv[5]); pk4.w = packbf2(bv[6], bv[7]);
    short8 bfr = __builtin_bit_cast(short8, pk4);
#pragma unroll
    for (int i = 0; i < 4; ++i) {
      short8 afr = *(const short8*)(Wo + (size_t)(m0 + 16 * i + lo) * NH + kc * 32 + g * 8);
      acc[i] = MFMA16(afr, bfr, acc[i]);
    }
  }
#pragma unroll
  for (int i = 0; i < 4; ++i)
#pragma unroll
    for (int r = 0; r < 4; ++r) {
      int c = m0 + 16 * i + g * 4 + r;
      size_t xo = ((size_t)(n * NC + c)) * LSP + col;
      out[xo] = acc[i][r] + ob[c] + x[xo] * gate[n * NC + c];
    }
}

extern "C" void kernel_launch(void* const* d_in, const int* in_sizes, int n_in,
                              void* d_out, int out_size, void* d_ws, size_t ws_size,
                              hipStream_t stream) {
  const float* x       = (const float*)d_in[0];
  const float* cfc     = (const float*)d_in[1];
  const float* theta_w = (const float*)d_in[2];
  const float* theta_b = (const float*)d_in[3];
  const float* phi_w   = (const float*)d_in[4];
  const float* phi_b   = (const float*)d_in[5];
  const float* g_w     = (const float*)d_in[6];
  const float* g_b     = (const float*)d_in[7];
  const float* out_w   = (const float*)d_in[8];
  const float* out_b   = (const float*)d_in[9];
  float* out = (float*)d_out;

  char* p = (char*)d_ws;
  auto alloc = [&](size_t bytes) { char* r = p; p += (bytes + 255) & ~(size_t)255; return r; };
  float* gate  = (float*)alloc(4 * NC * sizeof(float));
  bf16* s_t    = (bf16*)alloc((size_t)4 * LSP * NC * 2);          // [n][l][c]
  bf16* thph   = (bf16*)alloc((size_t)4 * LSP * 256 * 2);         // [n][l][th|ph]
  bf16* gTb    = (bf16*)alloc((size_t)4 * NH * LSP * 2);          // [n][o][l]
  bf16* wbf    = (bf16*)alloc((size_t)4 * 32768 * 2);             // thW|phW|gW|outW
  float* bcat  = (float*)alloc(256 * sizeof(float));              // theta_b|phi_b
  bf16* Opart  = (bf16*)alloc((size_t)SPLIT * 4 * LSP * NH * 2);  // [s][n][l][d]
  float* ml    = (float*)alloc((size_t)SPLIT * 4 * LSP * 2 * 4);  // [s][n][l][2]

  k_pre<<<1536, 256, 0, stream>>>(theta_w, phi_w, g_w, out_w, theta_b, phi_b,
                                  wbf, bcat, x, cfc, gate);
  k_scale_t<<<dim3(16, 8, 4), 256, 0, stream>>>(x, gate, s_t);
  k_gemms<<<dim3(384, 1, 4), 256, 0, stream>>>(s_t, wbf, bcat, g_b, thph, gTb);
  k_attn<<<dim3(LSP / 256, SPLIT, 4), 256, 0, stream>>>(thph, gTb, Opart, ml);
  k_final<<<dim3(256, 1, 4), 256, 0, stream>>>(wbf + 98304, Opart, ml, x, gate, out_b, out);
}

// Round 4
// 197.366 us; speedup vs baseline: 1.0794x; 1.0794x over previous
//
#include <hip/hip_runtime.h>
#include <hip/hip_bf16.h>

#define LSP 4096   // L = H*W
#define NC  256    // C
#define NH  128    // C/2
#define KB  64     // kv tile
#define QW  32     // q rows per wave (8 waves x 32 = 256 q / block)
#define SPLIT 4    // kv split factor
#define NTILE ((LSP / SPLIT) / KB)   // 16

typedef __attribute__((ext_vector_type(8))) short short8;
typedef __attribute__((ext_vector_type(4))) float f32x4;
typedef __attribute__((ext_vector_type(4))) unsigned int u32x4;
typedef __attribute__((ext_vector_type(2))) unsigned int u32x2;
typedef __hip_bfloat16 bf16;

#define MFMA16(a,b,c) __builtin_amdgcn_mfma_f32_16x16x32_bf16((a),(b),(c),0,0,0)

typedef __attribute__((address_space(1))) const void gas_t;
typedef __attribute__((address_space(3))) void las_t;
#define GLDS16(g, l) __builtin_amdgcn_global_load_lds((gas_t*)(g), (las_t*)(l), 16, 0, 0)

static __device__ __forceinline__ unsigned short f2bf(float f) {
  bf16 h = __float2bfloat16(f);
  return __builtin_bit_cast(unsigned short, h);
}
static __device__ __forceinline__ unsigned int packbf2(float a, float b) {
  return (unsigned int)f2bf(a) | ((unsigned int)f2bf(b) << 16);
}
static __device__ __forceinline__ float bf2f(unsigned short u) {
  return __builtin_bit_cast(float, (unsigned int)u << 16);
}
static __device__ __forceinline__ unsigned short bfu(bf16 h) {
  return __builtin_bit_cast(unsigned short, h);
}

// ---------- merged: weights->bf16 + bias concat (blocks 0..511) | SRM stats (512..1535)
__global__ __launch_bounds__(256) void k_pre(const float* __restrict__ a0,
    const float* __restrict__ a1, const float* __restrict__ a2,
    const float* __restrict__ a3, const float* __restrict__ tb,
    const float* __restrict__ pb, bf16* __restrict__ dst, float* __restrict__ bcat,
    const float* __restrict__ x, const float* __restrict__ cfc,
    float* __restrict__ gate) {
  int b = blockIdx.x;
  if (b < 512) {
    int i = b * 256 + threadIdx.x;
    int seg = i >> 15, off = i & 32767;
    const float* s = (seg == 0) ? a0 : (seg == 1) ? a1 : (seg == 2) ? a2 : a3;
    dst[i] = __float2bfloat16(s[off]);
    if (b == 0)
      bcat[threadIdx.x] = threadIdx.x < 128 ? tb[threadIdx.x] : pb[threadIdx.x - 128];
    return;
  }
  int nc = b - 512;   // n*C + c
  const float4* x4 = (const float4*)(x + (size_t)nc * LSP);
  float s = 0.f, q = 0.f;
  for (int i = threadIdx.x; i < LSP / 4; i += 256) {
    float4 v = x4[i];
    s += v.x + v.y + v.z + v.w;
    q += v.x * v.x + v.y * v.y + v.z * v.z + v.w * v.w;
  }
#pragma unroll
  for (int o = 32; o > 0; o >>= 1) { s += __shfl_xor(s, o); q += __shfl_xor(q, o); }
  __shared__ float rs[4], rq[4];
  int w = threadIdx.x >> 6;
  if ((threadIdx.x & 63) == 0) { rs[w] = s; rq[w] = q; }
  __syncthreads();
  if (threadIdx.x == 0) {
    float S = rs[0] + rs[1] + rs[2] + rs[3];
    float Q = rq[0] + rq[1] + rq[2] + rq[3];
    float mean = S / (float)LSP;
    float var = (Q - S * S / (float)LSP) / (float)(LSP - 1) + 1e-5f;
    float sd = sqrtf(var);
    int c = nc & (NC - 1);
    float z = mean * cfc[2 * c] + sd * cfc[2 * c + 1];
    gate[nc] = 1.f / (1.f + __expf(-z));
  }
}

// ---------- s_t[n][l][c] = bf16(x[n][c][l]*gate[n][c]), LDS-tiled transpose --
// 64l x 64c tile: coalesced 256B reads along l, coalesced 128B writes along c.
__global__ __launch_bounds__(256) void k_scale_t(const float* __restrict__ x,
    const float* __restrict__ gate, bf16* __restrict__ s_t) {
  __shared__ bf16 T[64][66];   // [c][l], +2 pad breaks phase-2 bank conflicts
  int n = blockIdx.z;
  int c0 = blockIdx.y * 64;
  int l0 = blockIdx.x * 64;
  int tid = threadIdx.x;
  int lr = tid & 63, cr = tid >> 6;
#pragma unroll
  for (int k = 0; k < 16; ++k) {
    int c = cr * 16 + k;
    float gv = gate[n * NC + c0 + c];
    float v = x[((size_t)(n * NC + c0 + c)) * LSP + l0 + lr] * gv;
    T[c][lr] = __float2bfloat16(v);
  }
  __syncthreads();
  int cg = tid & 7, lw = tid >> 3;   // 32 l-rows per pass
#pragma unroll
  for (int ps = 0; ps < 2; ++ps) {
    int l = lw + ps * 32;
    unsigned int pk[4];
#pragma unroll
    for (int e = 0; e < 4; ++e)
      pk[e] = (unsigned int)bfu(T[cg * 8 + 2 * e][l]) |
              ((unsigned int)bfu(T[cg * 8 + 2 * e + 1][l]) << 16);
    *(u32x4*)(s_t + ((size_t)n * LSP + l0 + l) * NC + c0 + cg * 8) =
        *(const u32x4*)pk;
  }
}

// ---------- generic NT GEMM body: D[M,N] = A[M,K] * B[N,K]^T + bias ----------
static __device__ __forceinline__ void gemm_nt_body(const bf16* __restrict__ A,
    const bf16* __restrict__ B, const float* __restrict__ bias, int bias_row,
    bf16* __restrict__ D, int Nd, int Kd, int bx) {
  int tn = Nd >> 6;
  int m0 = (bx / tn) * 64, n0 = (bx % tn) * 64;
  int tid = threadIdx.x, w = tid >> 6, lane = tid & 63;
  int lo = lane & 15, g = lane >> 4;
  f32x4 zero = {0.f, 0.f, 0.f, 0.f};
  f32x4 acc[4];
#pragma unroll
  for (int i = 0; i < 4; ++i) acc[i] = zero;
  for (int kc = 0; kc < Kd; kc += 32) {
    short8 bfr = *(const short8*)(B + (size_t)(n0 + w * 16 + lo) * Kd + kc + g * 8);
#pragma unroll
    for (int i = 0; i < 4; ++i) {
      short8 afr = *(const short8*)(A + (size_t)(m0 + 16 * i + lo) * Kd + kc + g * 8);
      acc[i] = MFMA16(afr, bfr, acc[i]);
    }
  }
  int col = n0 + w * 16 + lo;
#pragma unroll
  for (int i = 0; i < 4; ++i)
#pragma unroll
    for (int r = 0; r < 4; ++r) {
      int row = m0 + 16 * i + g * 4 + r;
      float bv = bias_row ? bias[row] : bias[col];
      D[(size_t)row * Nd + col] = __float2bfloat16(acc[i][r] + bv);
    }
}

// ---------- merged projection GEMMs: thph (bx<256) | gT (bx>=256) ----------
__global__ __launch_bounds__(256) void k_gemms(const bf16* __restrict__ s_t,
    const bf16* __restrict__ wbf, const float* __restrict__ bcat,
    const float* __restrict__ g_b, bf16* __restrict__ thph, bf16* __restrict__ gTb) {
  int z = blockIdx.z, bx = blockIdx.x;
  if (bx < 256) {
    gemm_nt_body(s_t + (size_t)z * LSP * NC, wbf, bcat, 0,
                 thph + (size_t)z * LSP * 256, 256, NC, bx);
  } else {
    gemm_nt_body(wbf + 65536, s_t + (size_t)z * LSP * NC, g_b, 1,
                 gTb + (size_t)z * NH * LSP, LSP, NC, bx - 256);
  }
}

// ---------- flash attention: 8 waves x 32 q, kv-split, 3-deep counted vmcnt --
__global__ __launch_bounds__(512, 2) void k_attn(const bf16* __restrict__ thph,
    const bf16* __restrict__ gT, bf16* __restrict__ Opart, float* __restrict__ ml) {
  __shared__ bf16 Kl[3][KB * NH];    // [j][k] 256B rows, chunk ^= (j&7)   48 KB
  __shared__ bf16 Vl[3][NH * KB];    // [d][j] 128B rows, chunk ^= (d&7)   48 KB
  __shared__ bf16 Pl[8][QW * KB];    // per-wave [q][j] 128B rows, ^(q&7)  32 KB

  const int n = blockIdx.z, sp = blockIdx.y;
  const int tid = threadIdx.x, w = tid >> 6, lane = tid & 63;
  const int lo = lane & 15, g = lane >> 4;
  const int swz = (lo & 7) << 4;

  const bf16* thn = thph + (size_t)n * LSP * 256;
  const bf16* gv  = gT + (size_t)n * NH * LSP;
  const int q0 = blockIdx.x * 256 + w * QW;
  const int j0base = sp * (LSP / SPLIT);

  // Q B-frags (loop-invariant, 32 VGPR)
  short8 qf[2][4];
#pragma unroll
  for (int qs = 0; qs < 2; ++qs)
#pragma unroll
    for (int kc = 0; kc < 4; ++kc)
      qf[qs][kc] = *(const short8*)(thn + (size_t)(q0 + qs * 16 + lo) * 256 + kc * 32 + g * 8);

  // staging offsets: source pre-swizzled, LDS dest linear (rule 21).
  // 512 threads, 2 chunks each for K and V; 4 loads/thread/stage.
  size_t koff[2], voff[2];
  int ldso[2];
#pragma unroll
  for (int i = 0; i < 2; ++i) {
    int ci = i * 512 + tid;
    int kj = ci >> 4, kcc = ci & 15;
    koff[i] = (size_t)kj * 256 + 128 + ((kcc ^ (kj & 7)) * 8);
    int vd = ci >> 3, vc2 = ci & 7;
    voff[i] = (size_t)vd * LSP + ((vc2 ^ (vd & 7)) * 8);
    ldso[i] = ci * 16;
  }

#define STAGE(JT, BUF) do { \
    const bf16* ksrc = thn + (size_t)(j0base + (JT) * KB) * 256; \
    const bf16* vsrc = gv + (j0base + (JT) * KB); \
    char* kdst = (char*)&Kl[BUF][0]; \
    char* vdst = (char*)&Vl[BUF][0]; \
    _Pragma("unroll") \
    for (int i = 0; i < 2; ++i) { \
      GLDS16(ksrc + koff[i], kdst + ldso[i]); \
      GLDS16(vsrc + voff[i], vdst + ldso[i]); \
    } } while (0)

  f32x4 zero = {0.f, 0.f, 0.f, 0.f};
  f32x4 acc[2][8];
#pragma unroll
  for (int qs = 0; qs < 2; ++qs)
#pragma unroll
    for (int dc = 0; dc < 8; ++dc) acc[qs][dc] = zero;
  float mv[2] = {-1e30f, -1e30f};
  float ls[2] = {0.f, 0.f};

  STAGE(0, 0);
  STAGE(1, 1);

  char* pwb = (char*)&Pl[w][0];

  for (int t = 0; t < NTILE; ++t) {
    int cur = t % 3;
    // drain own tile-t loads (leave t+1's 4 in flight), then block-sync
    if (t < NTILE - 1) asm volatile("s_waitcnt vmcnt(4)" ::: "memory");
    else               asm volatile("s_waitcnt vmcnt(0)" ::: "memory");
    __builtin_amdgcn_sched_barrier(0);
    __builtin_amdgcn_s_barrier();
    __builtin_amdgcn_sched_barrier(0);
    if (t + 2 < NTILE) STAGE(t + 2, (t + 2) % 3);   // into buffer freed by t-1

    const char* Kb = (const char*)&Kl[cur][0];
    const char* Vb = (const char*)&Vl[cur][0];

    // K-frag register cache: read K tile once, reuse across both q-subtiles
    short8 kfr[4][4];   // [jt][kc]
#pragma unroll
    for (int jt = 0; jt < 4; ++jt)
#pragma unroll
      for (int kc = 0; kc < 4; ++kc)
        kfr[jt][kc] = *(const short8*)(Kb + (jt * 16 + lo) * 256 + ((kc * 64 + g * 16) ^ swz));

    // S^T: ST[j][q] = sum_k K[j][k] Q[q][k]
    f32x4 st[2][4];
#pragma unroll
    for (int qs = 0; qs < 2; ++qs)
#pragma unroll
      for (int jt = 0; jt < 4; ++jt) st[qs][jt] = zero;
    __builtin_amdgcn_s_setprio(1);
#pragma unroll
    for (int kc = 0; kc < 4; ++kc)
#pragma unroll
      for (int jt = 0; jt < 4; ++jt) {
        st[0][jt] = MFMA16(kfr[jt][kc], qf[0][kc], st[0][jt]);
        st[1][jt] = MFMA16(kfr[jt][kc], qf[1][kc], st[1][jt]);
      }
    __builtin_amdgcn_s_setprio(0);

#pragma unroll
    for (int qs = 0; qs < 2; ++qs) {
      // tile max for q = lo (replicated over lane-groups)
      float t0 = fmaxf(fmaxf(st[qs][0][0], st[qs][0][1]), fmaxf(st[qs][0][2], st[qs][0][3]));
      float t1 = fmaxf(fmaxf(st[qs][1][0], st[qs][1][1]), fmaxf(st[qs][1][2], st[qs][1][3]));
      float t2 = fmaxf(fmaxf(st[qs][2][0], st[qs][2][1]), fmaxf(st[qs][2][2], st[qs][2][3]));
      float t3 = fmaxf(fmaxf(st[qs][3][0], st[qs][3][1]), fmaxf(st[qs][3][2], st[qs][3][3]));
      float tq = fmaxf(fmaxf(t0, t1), fmaxf(t2, t3));
      tq = fmaxf(tq, __shfl_xor(tq, 16));
      tq = fmaxf(tq, __shfl_xor(tq, 32));

      // defer-max (T13, THR=8)
      if (__any(tq > mv[qs] + 8.f)) {
        float nm = fmaxf(mv[qs], tq);
        float a = __expf(mv[qs] - nm);
        mv[qs] = nm; ls[qs] *= a;
#pragma unroll
        for (int r = 0; r < 4; ++r) {
          float b = __shfl(a, g * 4 + r);
#pragma unroll
          for (int dc = 0; dc < 8; ++dc) acc[qs][dc][r] *= b;
        }
      }

      // P = exp(S - m) -> swizzled per-wave LDS
      float mm = mv[qs], psum = 0.f;
      int rowb = (qs * 16 + lo) * 128;
#pragma unroll
      for (int jt = 0; jt < 4; ++jt) {
        float e0 = __expf(st[qs][jt][0] - mm);
        float e1 = __expf(st[qs][jt][1] - mm);
        float e2 = __expf(st[qs][jt][2] - mm);
        float e3 = __expf(st[qs][jt][3] - mm);
        psum += (e0 + e1) + (e2 + e3);
        u32x2 pk;
        pk.x = packbf2(e0, e1);
        pk.y = packbf2(e2, e3);
        *(u32x2*)(pwb + rowb + ((jt * 32 + g * 8) ^ swz)) = pk;
      }
      psum += __shfl_xor(psum, 16);
      psum += __shfl_xor(psum, 32);
      ls[qs] += psum;
    }

    asm volatile("" ::: "memory");  // order P ds_writes before ds_reads
    // PV: V-frag shared across both q-subtiles
#pragma unroll
    for (int kc2 = 0; kc2 < 2; ++kc2) {
      int kbb = kc2 * 64 + g * 16;
      short8 pa0 = *(const short8*)(pwb + lo * 128 + (kbb ^ swz));
      short8 pa1 = *(const short8*)(pwb + (16 + lo) * 128 + (kbb ^ swz));
      __builtin_amdgcn_s_setprio(1);
#pragma unroll
      for (int dc = 0; dc < 8; ++dc) {
        int d = dc * 16 + lo;
        short8 vb = *(const short8*)(Vb + d * 128 + (kbb ^ ((d & 7) << 4)));
        acc[0][dc] = MFMA16(pa0, vb, acc[0][dc]);
        acc[1][dc] = MFMA16(pa1, vb, acc[1][dc]);
      }
      __builtin_amdgcn_s_setprio(0);
    }
  }

  // epilogue: unnormalized partial O (bf16) + (m, lsum)
  bf16* opb = Opart + ((size_t)(sp * 4 + n) * LSP + q0) * NH;
#pragma unroll
  for (int qs = 0; qs < 2; ++qs)
#pragma unroll
    for (int dc = 0; dc < 8; ++dc)
#pragma unroll
      for (int r = 0; r < 4; ++r)
        opb[(size_t)(qs * 16 + g * 4 + r) * NH + dc * 16 + lo] =
            __float2bfloat16(acc[qs][dc][r]);
  if (g == 0) {
    float2* mlp = (float2*)ml + (size_t)(sp * 4 + n) * LSP + q0;
#pragma unroll
    for (int qs = 0; qs < 2; ++qs)
      mlp[qs * 16 + lo] = make_float2(mv[qs], ls[qs]);
  }
#undef STAGE
}

// ---------- fused combine + out-proj + residual ----------
__global__ __launch_bounds__(256) void k_final(const bf16* __restrict__ Wo,
    const bf16* __restrict__ Opart, const float* __restrict__ ml,
    const float* __restrict__ x, const float* __restrict__ gate,
    const float* __restrict__ ob, float* __restrict__ out) {
  int n = blockIdx.z;
  int m0 = (blockIdx.x >> 6) * 64, n0 = (blockIdx.x & 63) * 64;
  int tid = threadIdx.x, w = tid >> 6, lane = tid & 63;
  int lo = lane & 15, g = lane >> 4;
  int col = n0 + w * 16 + lo;

  float sc[SPLIT];
  {
    float2 m4[SPLIT];
    float mx = -1e30f;
#pragma unroll
    for (int s = 0; s < SPLIT; ++s) {
      m4[s] = ((const float2*)ml)[(size_t)(s * 4 + n) * LSP + col];
      mx = fmaxf(mx, m4[s].x);
    }
    float den = 0.f;
#pragma unroll
    for (int s = 0; s < SPLIT; ++s) { sc[s] = __expf(m4[s].x - mx); den += m4[s].y * sc[s]; }
    float inv = 1.f / den;
#pragma unroll
    for (int s = 0; s < SPLIT; ++s) sc[s] *= inv;
  }

  f32x4 zero = {0.f, 0.f, 0.f, 0.f};
  f32x4 acc[4];
#pragma unroll
  for (int i = 0; i < 4; ++i) acc[i] = zero;
#pragma unroll
  for (int kc = 0; kc < 4; ++kc) {
    float bv[8] = {0.f, 0.f, 0.f, 0.f, 0.f, 0.f, 0.f, 0.f};
#pragma unroll
    for (int s = 0; s < SPLIT; ++s) {
      short8 v = *(const short8*)(Opart + ((size_t)(s * 4 + n) * LSP + col) * NH + kc * 32 + g * 8);
#pragma unroll
      for (int e = 0; e < 8; ++e)
        bv[e] += sc[s] * bf2f((unsigned short)v[e]);
    }
    u32x4 pk4;
    pk4.x = packbf2(bv[0], bv[1]); pk4.y = packbf2(bv[2], bv[3]);
    pk4.z = packbf2(bv[4], bv[5]); pk4.w = packbf2(bv[6], bv[7]);
    short8 bfr = __builtin_bit_cast(short8, pk4);
#pragma unroll
    for (int i = 0; i < 4; ++i) {
      short8 afr = *(const short8*)(Wo + (size_t)(m0 + 16 * i + lo) * NH + kc * 32 + g * 8);
      acc[i] = MFMA16(afr, bfr, acc[i]);
    }
  }
#pragma unroll
  for (int i = 0; i < 4; ++i)
#pragma unroll
    for (int r = 0; r < 4; ++r) {
      int c = m0 + 16 * i + g * 4 + r;
      size_t xo = ((size_t)(n * NC + c)) * LSP + col;
      out[xo] = acc[i][r] + ob[c] + x[xo] * gate[n * NC + c];
    }
}

extern "C" void kernel_launch(void* const* d_in, const int* in_sizes, int n_in,
                              void* d_out, int out_size, void* d_ws, size_t ws_size,
                              hipStream_t stream) {
  const float* x       = (const float*)d_in[0];
  const float* cfc     = (const float*)d_in[1];
  const float* theta_w = (const float*)d_in[2];
  const float* theta_b = (const float*)d_in[3];
  const float* phi_w   = (const float*)d_in[4];
  const float* phi_b   = (const float*)d_in[5];
  const float* g_w     = (const float*)d_in[6];
  const float* g_b     = (const float*)d_in[7];
  const float* out_w   = (const float*)d_in[8];
  const float* out_b   = (const float*)d_in[9];
  float* out = (float*)d_out;

  char* p = (char*)d_ws;
  auto alloc = [&](size_t bytes) { char* r = p; p += (bytes + 255) & ~(size_t)255; return r; };
  float* gate  = (float*)alloc(4 * NC * sizeof(float));
  bf16* s_t    = (bf16*)alloc((size_t)4 * LSP * NC * 2);          // [n][l][c]
  bf16* thph   = (bf16*)alloc((size_t)4 * LSP * 256 * 2);         // [n][l][th|ph]
  bf16* gTb    = (bf16*)alloc((size_t)4 * NH * LSP * 2);          // [n][o][l]
  bf16* wbf    = (bf16*)alloc((size_t)4 * 32768 * 2);             // thW|phW|gW|outW
  float* bcat  = (float*)alloc(256 * sizeof(float));              // theta_b|phi_b
  bf16* Opart  = (bf16*)alloc((size_t)SPLIT * 4 * LSP * NH * 2);  // [s][n][l][d]
  float* ml    = (float*)alloc((size_t)SPLIT * 4 * LSP * 2 * 4);  // [s][n][l][2]

  k_pre<<<1536, 256, 0, stream>>>(theta_w, phi_w, g_w, out_w, theta_b, phi_b,
                                  wbf, bcat, x, cfc, gate);
  k_scale_t<<<dim3(64, 4, 4), 256, 0, stream>>>(x, gate, s_t);
  k_gemms<<<dim3(384, 1, 4), 256, 0, stream>>>(s_t, wbf, bcat, g_b, thph, gTb);
  k_attn<<<dim3(LSP / 256, SPLIT, 4), 512, 0, stream>>>(thph, gTb, Opart, ml);
  k_final<<<dim3(256, 1, 4), 256, 0, stream>>>(wbf + 98304, Opart, ml, x, gate, out_b, out);
}